// Round 4
// baseline (153.567 us; speedup 1.0000x reference)
//
#include <hip/hip_runtime.h>

#define TT 1024
#define CC 128
#define LL 128
#define EPSF 1e-7f
#define LN2F 0.69314718055994531f

#define LOG2F(x) __builtin_amdgcn_logf(x)

typedef unsigned int uint;
typedef uint uintx4 __attribute__((ext_vector_type(4)));
typedef float floatx4 __attribute__((ext_vector_type(4)));

template <int CTRL>
__device__ __forceinline__ int dpp_i(int old_, int x) {
  return __builtin_amdgcn_update_dpp(old_, x, CTRL, 0xf, 0xf, false);
}
// shift a3 to next lane (wave_shr:1); lane 0 receives 0.0f via bound_ctrl
__device__ __forceinline__ float dpp_shr1_f32(float x) {
  return __uint_as_float((uint)__builtin_amdgcn_update_dpp(
      0, (int)__float_as_uint(x), 0x138, 0xf, 0xf, true));
}

// fp32 -> bf16 bits, round-to-nearest-even (inputs finite positive)
__device__ __forceinline__ uint bf16bits(float x) {
  uint u = __float_as_uint(x);
  return (u + 0x7fffu + ((u >> 16) & 1u)) >> 16;
}

// async global->LDS: LDS dest = base + lane*size (wave-uniform base),
// global src = per-lane address. vmcnt-counted, zero VGPR cost.
#define GL16(gp, lp)                                            \
  __builtin_amdgcn_global_load_lds(                             \
      (const __attribute__((address_space(1))) void*)(gp),      \
      (__attribute__((address_space(3))) void*)(lp), 16, 0, 0)
#define GL4(gp, lp)                                             \
  __builtin_amdgcn_global_load_lds(                             \
      (const __attribute__((address_space(1))) void*)(gp),      \
      (__attribute__((address_space(3))) void*)(lp), 4, 0, 0)

// ---- prep (parallel): normalized emission probs, transposed for the scan ----
// Block = 512 threads = 8 waves; block handles (b, 8 consecutive t).
//   ET[b][t4][L] (uint4 over t in group-of-4: bf16 p[lab 2L] | p[lab 2L+1])
//   EB[b][t] (fp32 blank prob)
__global__ __launch_bounds__(512) void prep_kernel(const int* __restrict__ yt,
                                                   const float* __restrict__ yp,
                                                   uint* __restrict__ ET,
                                                   float* __restrict__ EB) {
  const int tid = threadIdx.x;
  const int w = tid >> 6;  // wave 0..7
  const int L = tid & 63;
  const int b = blockIdx.x >> 7;
  const int tg = blockIdx.x & 127;
  const int t = tg * 8 + w;

  __shared__ float rowp[8][130];  // normalized probs per wave-row
  __shared__ uint tp[64][9];      // [L][w] transpose buffer (+1 pad)

  const float* P = yp + ((size_t)b * TT + t) * CC;
  const float2 v = *(const float2*)(P + 2 * L);
  float x = (v.x + EPSF) + (v.y + EPSF);
#pragma unroll
  for (int off = 32; off > 0; off >>= 1) x += __shfl_xor(x, off);
  const float r = 1.0f / x;
  const float er = EPSF * r;
  *(float2*)&rowp[w][2 * L] =
      make_float2(__builtin_fmaf(v.x, r, er), __builtin_fmaf(v.y, r, er));
  const int2 lab = *(const int2*)(yt + b * LL + 2 * L);
  if (L == 63) EB[b * TT + t] = __builtin_fmaf(v.y, r, er);  // c=127 blank
  __syncthreads();
  const float p1 = rowp[w][lab.x];
  const float p2 = rowp[w][lab.y];
  tp[L][w] = (bf16bits(p2) << 16) | bf16bits(p1);
  __syncthreads();
  if (tid < 128) {  // 2 t4-groups x 64 lanes, coalesced uint4 stores
    const int g4 = tid >> 6, Lo = tid & 63;
    uint4 val;
    val.x = tp[Lo][g4 * 4 + 0];
    val.y = tp[Lo][g4 * 4 + 1];
    val.z = tp[Lo][g4 * 4 + 2];
    val.w = tp[Lo][g4 * 4 + 3];
    ((uint4*)ET)[((size_t)(b * 256 + tg * 2 + g4) << 6) + Lo] = val;
  }
}

// ---- serial scan: fp32 linear-domain scaled forward, one wave per b ----
// Lane L owns states 4L..4L+3 (lane63's extra a4 is state 256). alpha_true =
// a * 2^ell, wave-uniform ell; max pinned near 2^100, rescale every 16 steps.
//
// Memory pipeline (post-mortems r1-r3): register-ring prefetch spills
// (r1: VGPR=40, r3: VGPR=72 + scratch round-trips) -> depth must live in
// LDS. r2's GL16->LDS ring with counted vmcnt worked on the HBM side; its
// residual stall was the LDS->reg hop (compiler ds_reads with ~1-group
// lead vs ~130cy DS latency). Now the ds_reads are inline-asm with a
// 4-deep register rotation: each group's pair (lane-indexed et b128 +
// broadcast eb b128) is issued 3 groups (~350cy) ahead and consumed after
// a counted s_waitcnt lgkmcnt(6) (6 newer ds ops stay in flight; DS
// returns in-order; the loop has no other lgkm events). Consumed regs are
// tied "+v" to the wait so uses can't hoist. GL16 ring: 4 x 8-group
// buffers (32KB), issued 3 buffers ahead, counted vmcnt(16) — never 0.

// issue ds_read pair for the next pending group into set S, advance addrs
#define DSRD(S)                                                        \
  do {                                                                 \
    asm volatile("ds_read_b128 %0, %1"                                 \
                 : "=&v"(et##S) : "v"(etbase + etoff));                \
    asm volatile("ds_read_b128 %0, %1"                                 \
                 : "=&v"(eb##S) : "v"(ebbase + eboff));                \
    etoff = (etoff + 1024u) & 32767u;                                  \
    eboff = min(eboff + 16u, 4080u);                                   \
  } while (0)

// counted wait: set S's pair (issued 3 groups ago) is the oldest 2 of 8
// in-flight ds ops; ties make consumption depend on the wait
#define DSWAIT(S) \
  asm volatile("s_waitcnt lgkmcnt(6)" : "+v"(et##S), "+v"(eb##S))

// one lattice step using word wv (bf16 pair) and blank prob pbf
#define CTC_STEP(wv, pbf)                                   \
  do {                                                      \
    const float p1 = __uint_as_float((wv) << 16);           \
    const float p2 = __uint_as_float((wv) & 0xffff0000u);   \
    const float pb = (pbf);                                 \
    const float p3 = dpp_shr1_f32(a3);                      \
    const float n0 = (a0 + p3) * pb;                        \
    const float n1 = __builtin_fmaf(s1f, p3, a0 + a1) * p1; \
    const float n2 = (a2 + a1) * pb;                        \
    const float n3 = __builtin_fmaf(s3f, a1, a3 + a2) * p2; \
    const float n4 = (a4 + a3) * pb;                        \
    a0 = n0; a1 = n1; a2 = n2; a3 = n3; a4 = n4;            \
  } while (0)

#define CTC_QUAD(et, eb)        \
  do {                          \
    CTC_STEP((et)[0], (eb)[0]); \
    CTC_STEP((et)[1], (eb)[1]); \
    CTC_STEP((et)[2], (eb)[2]); \
    CTC_STEP((et)[3], (eb)[3]); \
  } while (0)

// rescale wave-max exponent back to 2^100 (biased 227); e clamped so the
// correction factor stays a normal fp32 even after a catastrophic window
#define CTC_RESCALE()                                                \
  do {                                                               \
    const float m = fmaxf(fmaxf(fmaxf(a0, a1), fmaxf(a2, a3)), a4);  \
    int ke = (int)(__float_as_uint(m) >> 23);                        \
    ke = max(ke, dpp_i<0x111>(ke, ke));                              \
    ke = max(ke, dpp_i<0x112>(ke, ke));                              \
    ke = max(ke, dpp_i<0x114>(ke, ke));                              \
    ke = max(ke, dpp_i<0x118>(ke, ke));                              \
    ke = max(ke, dpp_i<0x142>(ke, ke));                              \
    ke = max(ke, dpp_i<0x143>(ke, ke));                              \
    ke = __builtin_amdgcn_readlane(ke, 63);                          \
    int e = ke - 227; /* biased_exp(max) - (127 + 100) */            \
    e = e < -127 ? -127 : e;                                         \
    const float sc = __uint_as_float((uint)(127 - e) << 23);         \
    a0 *= sc; a1 *= sc; a2 *= sc; a3 *= sc; a4 *= sc;                \
    ell += e;                                                        \
  } while (0)

__global__ __launch_bounds__(64) void scan_kernel(const int* __restrict__ yt,
                                                  const uint* __restrict__ ET,
                                                  const float* __restrict__ EB,
                                                  float* __restrict__ out) {
  const int b = blockIdx.x;
  const int L = threadIdx.x & 63;

  __shared__ uint4 ETl[32][64];   // 32 KB ring: 4 buffers x 8 groups
  __shared__ float4 EBl[256];     // 4 KB: all blank probs (float4/group)

  const int2 lab = *(const int2*)(yt + b * LL + 2 * L);
  const int labm1 = __shfl_up(lab.y, 1);
  const float s1f = ((L > 0) && (lab.x != labm1)) ? 1.0f : 0.0f;  // s=4L+1
  const float s3f = (lab.y != lab.x) ? 1.0f : 0.0f;               // s=4L+3

  const uintx4* Et = (const uintx4*)ET + ((size_t)b << 14) + L;  // [t4][64]
  const float* Bp = EB + b * TT;

  // prologue: all EB (16 x 4B), ET buffers 0..2 (24 x 16B)
#pragma unroll
  for (int k = 0; k < 16; ++k) GL4(Bp + k * 64 + L, (char*)EBl + k * 256);
#pragma unroll
  for (int g = 0; g < 24; ++g) GL16(Et + g * 64, (char*)ETl + g * 1024);
  // oldest 24 (EB + buffer 0) landed; buffers 1,2 may stay in flight
  asm volatile("s_waitcnt vmcnt(16)" ::: "memory");

  const uint etbase =
      (uint)(size_t)(__attribute__((address_space(3))) char*)(void*)ETl;
  const uint ebbase =
      (uint)(size_t)(__attribute__((address_space(3))) char*)(void*)EBl;
  uint etoff = (uint)L * 16u;  // group-0 address component (lane-folded)
  uint eboff = 0u;

  uintx4 et0, et1, et2, et3;
  floatx4 eb0, eb1, eb2, eb3;
  DSRD(0);  // group 0 -> set 0
  DSRD(1);  // group 1 -> set 1
  DSRD(2);  // group 2 -> set 2

  // virtual alpha_{-1}: state 0 = 2^100, rest 0; first step yields alpha_0
  float a0 = (L == 0) ? 0x1.0p100f : 0.0f;
  float a1 = 0.0f, a2 = 0.0f, a3 = 0.0f, a4 = 0.0f;
  int ell = -100;  // wave-uniform: alpha_true = a * 2^ell

  // 32 iterations x 32 steps (8 groups); rescale every 4 groups
#pragma unroll 1
  for (int kk = 0; kk < 32; ++kk) {
    {  // issue buffer kk+3 (8 x GL16); source clamped to last real buffer
      const int bb = (kk + 3 < 32) ? kk + 3 : 31;
      const uintx4* src = Et + (size_t)bb * 512;
      char* dst = (char*)ETl + (size_t)((kk + 3) & 3) * 8192;
#pragma unroll
      for (int g = 0; g < 8; ++g) GL16(src + g * 64, dst + g * 1024);
    }
    // buffers <= kk+1 landed; kk+2, kk+3 (16 loads) stay in flight
    asm volatile("s_waitcnt vmcnt(16)" ::: "memory");

    DSRD(3); DSWAIT(0); CTC_QUAD(et0, eb0);  // consume g0, issue g3
    DSRD(0); DSWAIT(1); CTC_QUAD(et1, eb1);  // consume g1, issue g4
    DSRD(1); DSWAIT(2); CTC_QUAD(et2, eb2);  // consume g2, issue g5
    DSRD(2); DSWAIT(3); CTC_QUAD(et3, eb3);  // consume g3, issue g6
    CTC_RESCALE();
    DSRD(3); DSWAIT(0); CTC_QUAD(et0, eb0);  // consume g4, issue g7
    DSRD(0); DSWAIT(1); CTC_QUAD(et1, eb1);  // consume g5, issue g8
    DSRD(1); DSWAIT(2); CTC_QUAD(et2, eb2);  // consume g6, issue g9
    DSRD(2); DSWAIT(3); CTC_QUAD(et3, eb3);  // consume g7, issue g10
    CTC_RESCALE();
  }

  if (L == 63) {
    // states 255 (=a3), 256 (=a4): loglik = ln2 * (ell + log2(a3+a4))
    float s = a3 + a4;
    if (s < 1e-37f) s = 1e-37f;  // stay normal; loud-but-finite floor
    out[b] = -LN2F * ((float)ell + LOG2F(s));
  }
}

extern "C" void kernel_launch(void* const* d_in, const int* in_sizes, int n_in,
                              void* d_out, int out_size, void* d_ws,
                              size_t ws_size, hipStream_t stream) {
  const int* yt = (const int*)d_in[0];
  const float* yp = (const float*)d_in[1];
  float* out = (float*)d_out;
  const int B = in_sizes[0] / LL;  // 128
  uint* ET = (uint*)d_ws;                                       // 33.55 MB
  float* EB = (float*)((char*)d_ws + (size_t)B * 64 * TT * 4);  // +512 KB
  hipLaunchKernelGGL(prep_kernel, dim3(B * 128), dim3(512), 0, stream, yt, yp,
                     ET, EB);
  hipLaunchKernelGGL(scan_kernel, dim3(B), dim3(64), 0, stream, yt, ET, EB,
                     out);
}

// Round 5
// 152.421 us; speedup vs baseline: 1.0075x; 1.0075x over previous
//
#include <hip/hip_runtime.h>

#define TT 1024
#define CC 128
#define LL 128
#define EPSF 1e-7f
#define LN2F 0.69314718055994531f

#define LOG2F(x) __builtin_amdgcn_logf(x)

typedef unsigned int uint;
typedef uint uintx4 __attribute__((ext_vector_type(4)));

template <int CTRL>
__device__ __forceinline__ int dpp_i(int old_, int x) {
  return __builtin_amdgcn_update_dpp(old_, x, CTRL, 0xf, 0xf, false);
}
// shift a3 to next lane (wave_shr:1); lane 0 receives 0.0f via bound_ctrl
__device__ __forceinline__ float dpp_shr1_f32(float x) {
  return __uint_as_float((uint)__builtin_amdgcn_update_dpp(
      0, (int)__float_as_uint(x), 0x138, 0xf, 0xf, true));
}

// fp32 -> bf16 bits, round-to-nearest-even (inputs finite positive)
__device__ __forceinline__ uint bf16bits(float x) {
  uint u = __float_as_uint(x);
  return (u + 0x7fffu + ((u >> 16) & 1u)) >> 16;
}

// async global->LDS: LDS dest = base + lane*size (wave-uniform base),
// global src = per-lane address. vmcnt-counted, zero VGPR cost.
#define GL16(gp, lp)                                            \
  __builtin_amdgcn_global_load_lds(                             \
      (const __attribute__((address_space(1))) void*)(gp),      \
      (__attribute__((address_space(3))) void*)(lp), 16, 0, 0)
#define GL4(gp, lp)                                             \
  __builtin_amdgcn_global_load_lds(                             \
      (const __attribute__((address_space(1))) void*)(gp),      \
      (__attribute__((address_space(3))) void*)(lp), 4, 0, 0)

// ---- prep (parallel): normalized emission probs, transposed for the scan ----
// Block = 512 threads = 8 waves; block handles (b, 8 consecutive t).
//   ET[b][t4][L] (uint4 over t in group-of-4: bf16 p[lab 2L] | p[lab 2L+1])
//   EB[b][t] (fp32 blank prob)
__global__ __launch_bounds__(512) void prep_kernel(const int* __restrict__ yt,
                                                   const float* __restrict__ yp,
                                                   uint* __restrict__ ET,
                                                   float* __restrict__ EB) {
  const int tid = threadIdx.x;
  const int w = tid >> 6;  // wave 0..7
  const int L = tid & 63;
  const int b = blockIdx.x >> 7;
  const int tg = blockIdx.x & 127;
  const int t = tg * 8 + w;

  __shared__ float rowp[8][130];  // normalized probs per wave-row
  __shared__ uint tp[64][9];      // [L][w] transpose buffer (+1 pad)

  const float* P = yp + ((size_t)b * TT + t) * CC;
  const float2 v = *(const float2*)(P + 2 * L);
  float x = (v.x + EPSF) + (v.y + EPSF);
#pragma unroll
  for (int off = 32; off > 0; off >>= 1) x += __shfl_xor(x, off);
  const float r = 1.0f / x;
  const float er = EPSF * r;
  *(float2*)&rowp[w][2 * L] =
      make_float2(__builtin_fmaf(v.x, r, er), __builtin_fmaf(v.y, r, er));
  const int2 lab = *(const int2*)(yt + b * LL + 2 * L);
  if (L == 63) EB[b * TT + t] = __builtin_fmaf(v.y, r, er);  // c=127 blank
  __syncthreads();
  const float p1 = rowp[w][lab.x];
  const float p2 = rowp[w][lab.y];
  tp[L][w] = (bf16bits(p2) << 16) | bf16bits(p1);
  __syncthreads();
  if (tid < 128) {  // 2 t4-groups x 64 lanes, coalesced uint4 stores
    const int g4 = tid >> 6, Lo = tid & 63;
    uint4 val;
    val.x = tp[Lo][g4 * 4 + 0];
    val.y = tp[Lo][g4 * 4 + 1];
    val.z = tp[Lo][g4 * 4 + 2];
    val.w = tp[Lo][g4 * 4 + 3];
    ((uint4*)ET)[((size_t)(b * 256 + tg * 2 + g4) << 6) + Lo] = val;
  }
}

// ---- serial scan: fp32 linear-domain scaled forward, producer/consumer ----
// Lane L owns states 4L..4L+3 (lane63's extra a4 is state 256). alpha_true =
// a * 2^ell, wave-uniform ell; max pinned near 2^100, rescale every 16 steps.
//
// r2 (GL16+compiler ds) and r4 (GL16+asm ds, 3-group lead) both plateau at
// ~100 cy/step with ~65 cy/step unexplained; r0->r1 (fp64->fp32) gained only
// 13% -> neither ds-latency- nor VALU-issue-bound. Hypothesis: compiler-
// inserted ordering waits between global_load_lds and ds_read on the same
// LDS object stall the mixed stream. Fix: WAVE SPECIALIZATION. Wave 1
// (producer) owns ALL VMEM: issues GL16 batches, waits counted vmcnt(8),
// absorbs any barrier drain (it has ~900cy slack/interval). Wave 0
// (consumer) has ZERO VMEM: pure ds_read + VALU + s_barrier. One barrier
// per 32-step buffer. Invariant: at the barrier opening interval k, buffer
// k+1 is LDS-resident (producer issued it in interval k-1 and vmcnt-waited).
// Consumer reads buffer k and pre-reads group 0 of k+1; producer writes slot
// (k+2)&3 — ring distance 2 from any read slot, race-free.

// one lattice step using word wv (bf16 pair) and blank prob pbf
#define CTC_STEP(wv, pbf)                                   \
  do {                                                      \
    const float p1 = __uint_as_float((wv) << 16);           \
    const float p2 = __uint_as_float((wv) & 0xffff0000u);   \
    const float pb = (pbf);                                 \
    const float p3 = dpp_shr1_f32(a3);                      \
    const float n0 = (a0 + p3) * pb;                        \
    const float n1 = __builtin_fmaf(s1f, p3, a0 + a1) * p1; \
    const float n2 = (a2 + a1) * pb;                        \
    const float n3 = __builtin_fmaf(s3f, a1, a3 + a2) * p2; \
    const float n4 = (a4 + a3) * pb;                        \
    a0 = n0; a1 = n1; a2 = n2; a3 = n3; a4 = n4;            \
  } while (0)

#define CTC_QUAD(et, eb)      \
  do {                        \
    CTC_STEP((et).x, (eb).x); \
    CTC_STEP((et).y, (eb).y); \
    CTC_STEP((et).z, (eb).z); \
    CTC_STEP((et).w, (eb).w); \
  } while (0)

// rescale wave-max exponent back to 2^100 (biased 227); e clamped so the
// correction factor stays a normal fp32 even after a catastrophic window
#define CTC_RESCALE()                                                \
  do {                                                               \
    const float m = fmaxf(fmaxf(fmaxf(a0, a1), fmaxf(a2, a3)), a4);  \
    int ke = (int)(__float_as_uint(m) >> 23);                        \
    ke = max(ke, dpp_i<0x111>(ke, ke));                              \
    ke = max(ke, dpp_i<0x112>(ke, ke));                              \
    ke = max(ke, dpp_i<0x114>(ke, ke));                              \
    ke = max(ke, dpp_i<0x118>(ke, ke));                              \
    ke = max(ke, dpp_i<0x142>(ke, ke));                              \
    ke = max(ke, dpp_i<0x143>(ke, ke));                              \
    ke = __builtin_amdgcn_readlane(ke, 63);                          \
    int e = ke - 227; /* biased_exp(max) - (127 + 100) */            \
    e = e < -127 ? -127 : e;                                         \
    const float sc = __uint_as_float((uint)(127 - e) << 23);         \
    a0 *= sc; a1 *= sc; a2 *= sc; a3 *= sc; a4 *= sc;                \
    ell += e;                                                        \
  } while (0)

__global__ __launch_bounds__(128) void scan_kernel(const int* __restrict__ yt,
                                                   const uint* __restrict__ ET,
                                                   const float* __restrict__ EB,
                                                   float* __restrict__ out) {
  const int b = blockIdx.x;
  const int tid = threadIdx.x;
  const int L = tid & 63;
  const int wv = tid >> 6;  // 0 = consumer, 1 = producer

  __shared__ uint4 ETl[4][8][64];  // 32 KB ring: 4 buffers x 8 groups
  __shared__ float4 EBl[256];      // 4 KB: all blank probs (float4/group)

  const int2 lab = *(const int2*)(yt + b * LL + 2 * L);
  const int labm1 = __shfl_up(lab.y, 1);
  const float s1f = ((L > 0) && (lab.x != labm1)) ? 1.0f : 0.0f;  // s=4L+1
  const float s3f = (lab.y != lab.x) ? 1.0f : 0.0f;               // s=4L+3

  const uintx4* Et = (const uintx4*)ET + ((size_t)b << 14) + L;  // [t4][64]
  const float* Bp = EB + b * TT;

  if (wv == 1) {  // producer prologue: all EB (16 x 4B) + buffers 0,1
#pragma unroll
    for (int k = 0; k < 16; ++k) GL4(Bp + k * 64 + L, (char*)EBl + k * 256);
#pragma unroll
    for (int g = 0; g < 16; ++g) GL16(Et + g * 64, (char*)ETl + g * 1024);
    // oldest 24 (EB + buffer 0) landed; buffer 1's 8 may stay in flight
    asm volatile("s_waitcnt vmcnt(8)" ::: "memory");
  }
  __syncthreads();  // buffer 0 ready

  uint4 etA, etB;
  float4 ebA, ebB;
  if (wv == 0) {
    etA = ((const uint4*)ETl)[L];
    ebA = EBl[0];
  }

  // virtual alpha_{-1}: state 0 = 2^100, rest 0; first step yields alpha_0
  float a0 = (wv == 0 && L == 0) ? 0x1.0p100f : 0.0f;
  float a1 = 0.0f, a2 = 0.0f, a3 = 0.0f, a4 = 0.0f;
  int ell = -100;  // wave-uniform: alpha_true = a * 2^ell

  // 32 intervals x 32 steps (8 groups); rescale every 4 groups
#pragma unroll 1
  for (int kk = 0; kk < 32; ++kk) {
    if (wv == 1) {
      // issue buffer kk+2 into slot (kk+2)&3 (tail: re-issue buffer 31)
      const int bb = (kk + 2 < 32) ? kk + 2 : 31;
      const uintx4* src = Et + (size_t)bb * 512;
      char* dst = (char*)ETl + (size_t)((kk + 2) & 3) * 8192;
#pragma unroll
      for (int g = 0; g < 8; ++g) GL16(src + g * 64, dst + g * 1024);
      // buffer kk+1 landed; buffer kk+2's 8 stay in flight (until the
      // __syncthreads drain, which this wave absorbs with ~900cy slack)
      asm volatile("s_waitcnt vmcnt(8)" ::: "memory");
    } else {
      // consume buffer kk (8 groups), 1-group-ahead A/B rotation
      const uint4* cur = (const uint4*)ETl + (size_t)(kk & 3) * 512;
      const int ebi = kk * 8;
      etB = cur[1 * 64 + L]; ebB = EBl[ebi + 1];
      CTC_QUAD(etA, ebA);  // g0
      etA = cur[2 * 64 + L]; ebA = EBl[ebi + 2];
      CTC_QUAD(etB, ebB);  // g1
      etB = cur[3 * 64 + L]; ebB = EBl[ebi + 3];
      CTC_QUAD(etA, ebA);  // g2
      etA = cur[4 * 64 + L]; ebA = EBl[ebi + 4];
      CTC_QUAD(etB, ebB);  // g3
      CTC_RESCALE();
      etB = cur[5 * 64 + L]; ebB = EBl[ebi + 5];
      CTC_QUAD(etA, ebA);  // g4
      etA = cur[6 * 64 + L]; ebA = EBl[ebi + 6];
      CTC_QUAD(etB, ebB);  // g5
      etB = cur[7 * 64 + L]; ebB = EBl[ebi + 7];
      CTC_QUAD(etA, ebA);  // g6
      // pre-read next buffer's group 0 (resident since interval start)
      etA = ((const uint4*)ETl)[(size_t)((kk + 1) & 3) * 512 + L];
      ebA = EBl[(ebi + 8 < 256) ? ebi + 8 : 255];
      CTC_QUAD(etB, ebB);  // g7
      CTC_RESCALE();
    }
    __syncthreads();
  }

  if (tid == 63) {  // consumer wave, lane 63
    // states 255 (=a3), 256 (=a4): loglik = ln2 * (ell + log2(a3+a4))
    float s = a3 + a4;
    if (s < 1e-37f) s = 1e-37f;  // stay normal; loud-but-finite floor
    out[b] = -LN2F * ((float)ell + LOG2F(s));
  }
}

extern "C" void kernel_launch(void* const* d_in, const int* in_sizes, int n_in,
                              void* d_out, int out_size, void* d_ws,
                              size_t ws_size, hipStream_t stream) {
  const int* yt = (const int*)d_in[0];
  const float* yp = (const float*)d_in[1];
  float* out = (float*)d_out;
  const int B = in_sizes[0] / LL;  // 128
  uint* ET = (uint*)d_ws;                                       // 33.55 MB
  float* EB = (float*)((char*)d_ws + (size_t)B * 64 * TT * 4);  // +512 KB
  hipLaunchKernelGGL(prep_kernel, dim3(B * 128), dim3(512), 0, stream, yt, yp,
                     ET, EB);
  hipLaunchKernelGGL(scan_kernel, dim3(B), dim3(128), 0, stream, yt, ET, EB,
                     out);
}